// Round 14
// baseline (234.845 us; speedup 1.0000x reference)
//
#include <hip/hip_runtime.h>
#include <hip/hip_bf16.h>

#define NTOK 19950
#define NTOKP 19968      // padded row for partials
#define KTOP 300
#define NB 8
#define NQ 2400          // NB * KTOP
#define QDIM 520         // 515 padded to 520
#define NCC 16           // c-chunks of 16
#define CAND 4096

typedef float f32x4 __attribute__((ext_vector_type(4)));

__device__ __forceinline__ uint32_t fkey(float f) {
    uint32_t u = __float_as_uint(f);
    return (u & 0x80000000u) ? ~u : (u | 0x80000000u);
}

// suffix sums over 256 bins: hist[i] <- sum_{j>=i} hist[j]; needs hist[256]==0.
__device__ __forceinline__ void suffix_scan_256(int* hist, int tid) {
    if (tid < 64) {
        const int c0 = hist[tid * 4], c1 = hist[tid * 4 + 1];
        const int c2 = hist[tid * 4 + 2], c3 = hist[tid * 4 + 3];
        const int tot = c0 + c1 + c2 + c3;
        int s = tot;
        #pragma unroll
        for (int off = 1; off < 64; off <<= 1) {
            int o = __shfl_down(s, off);
            if (tid + off < 64) s += o;
        }
        const int Sn = s - tot;
        hist[tid * 4 + 3] = c3 + Sn;
        hist[tid * 4 + 2] = c2 + c3 + Sn;
        hist[tid * 4 + 1] = c1 + c2 + c3 + Sn;
        hist[tid * 4 + 0] = tot + Sn;
    }
}

// ---------------- K1a: partial scores, contiguous-streaming reads ----------------
__global__ __launch_bounds__(256) void score_part_kernel(
    const float* __restrict__ f0, const float* __restrict__ f1, const float* __restrict__ f2,
    const float* __restrict__ conv_w, float* __restrict__ partial, int* __restrict__ ghist,
    int* __restrict__ cnt)
{
    __shared__ float cwch[16];
    const int tid = threadIdx.x;
    const int blk = blockIdx.x;
    int b, cc;
    if (blk < 512)      { b = blk >> 6; cc = (blk >> 2) & 15; }
    else if (blk < 640) { int i = blk - 512; b = i >> 4; cc = i & 15; }
    else                { int i = blk - 640; b = i >> 4; cc = i & 15; }
    if (blk >= 640 && ((blk - 640) & 15) == 0 && tid < 256)
        ghist[((blk - 640) >> 4) * 256 + tid] = 0;
    if (blk == 640 && tid < 16) cnt[tid] = 0;          // gcnt[8] + gccnt[8]
    if (tid < 16) cwch[tid] = conv_w[cc * 16 + tid];
    __syncthreads();

    if (blk < 512) {                       // f0: quarter q -> 950 f32x4 tile
        const int q = blk & 3;
        const f32x4* b4 = (const f32x4*)(f0 + ((size_t)(b * 256 + cc * 16)) * 15200) + q * 950;
        const int s3 = (tid + 768 < 950) ? tid + 768 : 0;
        f32x4 a0 = {0,0,0,0}, a1 = a0, a2 = a0, a3 = a0;
        #pragma unroll 4
        for (int c = 0; c < 16; ++c) {
            const f32x4* r = b4 + (size_t)c * 3800;
            const float w = cwch[c];
            f32x4 v0 = r[tid], v1 = r[tid + 256], v2 = r[tid + 512], v3 = r[s3];
            a0 += v0 * w; a1 += v1 * w; a2 += v2 * w; a3 += v3 * w;
        }
        f32x4* o4 = (f32x4*)(partial + (size_t)(cc * NB + b) * NTOKP) + q * 950;
        o4[tid] = a0; o4[tid + 256] = a1; o4[tid + 512] = a2;
        if (tid + 768 < 950) o4[tid + 768] = a3;
    } else if (blk < 640) {                // f1
        const f32x4* b4 = (const f32x4*)(f1 + ((size_t)(b * 256 + cc * 16)) * 3800);
        const int s3 = (tid + 768 < 950) ? tid + 768 : 0;
        f32x4 a0 = {0,0,0,0}, a1 = a0, a2 = a0, a3 = a0;
        #pragma unroll 4
        for (int c = 0; c < 16; ++c) {
            const f32x4* r = b4 + (size_t)c * 950;
            const float w = cwch[c];
            f32x4 v0 = r[tid], v1 = r[tid + 256], v2 = r[tid + 512], v3 = r[s3];
            a0 += v0 * w; a1 += v1 * w; a2 += v2 * w; a3 += v3 * w;
        }
        f32x4* o4 = (f32x4*)(partial + (size_t)(cc * NB + b) * NTOKP + 15200);
        o4[tid] = a0; o4[tid + 256] = a1; o4[tid + 512] = a2;
        if (tid + 768 < 950) o4[tid + 768] = a3;
    } else {                               // f2
        const float2* b2 = (const float2*)(f2 + ((size_t)(b * 256 + cc * 16)) * 950);
        const int s1 = (tid + 256 < 475) ? tid + 256 : 0;
        float2 a0 = {0,0}, a1 = a0;
        #pragma unroll 4
        for (int c = 0; c < 16; ++c) {
            const float2* r = b2 + (size_t)c * 475;
            const float w = cwch[c];
            float2 v0 = r[tid], v1 = r[s1];
            a0.x += v0.x * w; a0.y += v0.y * w;
            a1.x += v1.x * w; a1.y += v1.y * w;
        }
        float2* o2 = (float2*)(partial + (size_t)(cc * NB + b) * NTOKP + 19000);
        if (tid < 475) o2[tid] = a0;
        if (tid + 256 < 475) o2[tid + 256] = a1;
    }
}

// ---------------- K1b: reduce partials + per-batch top-byte histogram ----------------
__global__ __launch_bounds__(256) void score_reduce_kernel(
    const float* __restrict__ partial, const float* __restrict__ conv_b,
    float* __restrict__ scores, int* __restrict__ ghist)
{
    __shared__ int lh[256];
    const int tid = threadIdx.x;
    const int b = blockIdx.y;
    const int i = blockIdx.x * 256 + tid;
    lh[tid] = 0;
    __syncthreads();
    if (i < NTOK) {
        float s = 0.0f;
        #pragma unroll
        for (int cc = 0; cc < NCC; ++cc)
            s += partial[(size_t)(cc * NB + b) * NTOKP + i];
        s += conv_b[0];
        scores[b * NTOK + i] = s;
        atomicAdd(&lh[fkey(s) >> 24], 1);
    }
    __syncthreads();
    if (lh[tid]) atomicAdd(&ghist[b * 256 + tid], lh[tid]);
}

// ---------------- K2a: parallel emit (624 blocks): sure-selected + candidates ----------
__global__ __launch_bounds__(256) void topk_emit_kernel(
    const float* __restrict__ scores, const int* __restrict__ ghist,
    int* __restrict__ cnt, int* __restrict__ top_idx,
    uint32_t* __restrict__ cand_k, int* __restrict__ cand_i)
{
    __shared__ int sfx[257];
    __shared__ int s_v;
    const int tid = threadIdx.x;
    const int b = blockIdx.y;
    const int i = blockIdx.x * 256 + tid;
    sfx[tid] = ghist[b * 256 + tid];
    if (tid == 0) sfx[256] = 0;
    __syncthreads();
    suffix_scan_256(sfx, tid);
    __syncthreads();
    if (sfx[tid] >= KTOP && sfx[tid + 1] < KTOP) s_v = tid;
    __syncthreads();
    const uint32_t v = (uint32_t)s_v;
    if (i < NTOK) {
        uint32_t k = fkey(scores[b * NTOK + i]);
        uint32_t tb = k >> 24;
        if (tb > v) {
            int p = atomicAdd(&cnt[b], 1);
            top_idx[b * KTOP + p] = i;
        } else if (tb == v) {
            int p = atomicAdd(&cnt[8 + b], 1);
            if (p < CAND) { cand_k[b * CAND + p] = k; cand_i[b * CAND + p] = i; }
        }
    }
}

// ---------------- K2b: refine boundary bucket (8 small blocks) ----------------
__global__ __launch_bounds__(256, 1) void topk_refine_kernel(
    const float* __restrict__ scores, const int* __restrict__ ghist,
    const int* __restrict__ cnt, int* __restrict__ top_idx,
    const uint32_t* __restrict__ cand_k, const int* __restrict__ cand_i)
{
    __shared__ int hist[257];
    __shared__ uint32_t ck[CAND];
    __shared__ int ci[CAND];
    __shared__ int tie[1024];
    __shared__ uint32_t s_prefix;
    __shared__ int s_Kr, s_cnt, s_tcnt;
    const int tid = threadIdx.x;
    const int b = blockIdx.x;

    hist[tid] = ghist[b * 256 + tid];
    if (tid == 0) { hist[256] = 0; s_tcnt = 0; }
    __syncthreads();
    suffix_scan_256(hist, tid);
    __syncthreads();
    if (hist[tid] >= KTOP && hist[tid + 1] < KTOP) {
        s_prefix = (uint32_t)tid << 24;
        s_Kr = KTOP - hist[tid + 1];
        s_cnt = hist[tid + 1];             // sure-selected count already emitted
    }
    __syncthreads();
    const uint32_t v = s_prefix >> 24;
    const int ccnt = cnt[8 + b];
    const bool fits = (ccnt <= CAND);
    const int ncand = fits ? ccnt : CAND;
    if (fits)
        for (int j = tid; j < ncand; j += 256) { ck[j] = cand_k[b * CAND + j]; ci[j] = cand_i[b * CAND + j]; }
    __syncthreads();

    uint32_t pmask = 0xFF000000u;
    for (int pass = 1; pass < 4; ++pass) {
        const int shift = 24 - 8 * pass;
        hist[tid] = 0;
        if (tid == 0) hist[256] = 0;
        __syncthreads();
        const uint32_t prefix = s_prefix;
        const int Kr = s_Kr;
        if (fits) {
            for (int j = tid; j < ncand; j += 256) {
                uint32_t k = ck[j];
                if ((k & pmask) == prefix) atomicAdd(&hist[(k >> shift) & 255], 1);
            }
        } else {
            for (int i = tid; i < NTOK; i += 256) {
                uint32_t k = fkey(scores[b * NTOK + i]);
                if ((k & pmask) == prefix) atomicAdd(&hist[(k >> shift) & 255], 1);
            }
        }
        __syncthreads();
        suffix_scan_256(hist, tid);
        __syncthreads();
        if (hist[tid] >= Kr && hist[tid + 1] < Kr) {
            s_prefix = prefix | ((uint32_t)tid << shift);
            s_Kr = Kr - hist[tid + 1];
        }
        __syncthreads();
        pmask |= (0xFFu << shift);
    }
    const uint32_t T = s_prefix;
    const int need = s_Kr;

    if (fits) {
        for (int j = tid; j < ncand; j += 256) {
            uint32_t k = ck[j];
            if (k > T) {
                int p = atomicAdd(&s_cnt, 1);
                top_idx[b * KTOP + p] = ci[j];
            } else if (k == T) {
                int p = atomicAdd(&s_tcnt, 1);
                if (p < 1024) tie[p] = ci[j];
            }
        }
    } else {
        for (int i = tid; i < NTOK; i += 256) {
            uint32_t k = fkey(scores[b * NTOK + i]);
            if ((k >> 24) == v) {
                if (k > T) {
                    int p = atomicAdd(&s_cnt, 1);
                    top_idx[b * KTOP + p] = i;
                } else if (k == T) {
                    int p = atomicAdd(&s_tcnt, 1);
                    if (p < 1024) tie[p] = i;
                }
            }
        }
    }
    __syncthreads();
    if (tid == 0) {
        const int base = KTOP - need;      // ties fill the tail deterministically
        int tcnt = s_tcnt > 1024 ? 1024 : s_tcnt;
        for (int s = 0; s < need; ++s) {   // 'need' smallest tie indices
            int mi = s;
            for (int u = s + 1; u < tcnt; ++u) if (tie[u] < tie[mi]) mi = u;
            int tmp = tie[s]; tie[s] = tie[mi]; tie[mi] = tmp;
            top_idx[b * KTOP + base + s] = tie[s];
        }
    }
}

// ---------------- K3: gather (fused) + MLP -> per-query gates G[2400][3] ----------------
#define QT 8
__global__ __launch_bounds__(512, 1) void mlp_kernel(
    const float* __restrict__ f0, const float* __restrict__ f1, const float* __restrict__ f2,
    const float* __restrict__ scores, const int* __restrict__ top_idx,
    const float* __restrict__ level_emb,
    const float* __restrict__ w1, const float* __restrict__ b1,
    const float* __restrict__ w2, const float* __restrict__ b2,
    const float* __restrict__ gate_w, const float* __restrict__ gate_b,
    float* __restrict__ G)
{
    __shared__ __align__(16) float q[QT][QDIM];
    __shared__ __align__(16) float part[QT][256];
    __shared__ __align__(16) float h[QT][256];
    __shared__ int s_b[QT], s_lvl[QT], s_hw[QT], s_HW[QT];
    const int tid = threadIdx.x;
    const int out = tid & 255;
    const int kh = tid >> 8;
    const int k0 = blockIdx.x * QT;

    if (tid < QT) {
        const int kk = k0 + tid;
        const int bq = kk / KTOP;
        const int idx = top_idx[kk];
        int lvl, hw, HWl, Wl, Hl;
        if (idx < 15200)      { lvl = 0; hw = idx;         HWl = 15200; Wl = 152; Hl = 100; }
        else if (idx < 19000) { lvl = 1; hw = idx - 15200; HWl = 3800;  Wl = 76;  Hl = 50;  }
        else                  { lvl = 2; hw = idx - 19000; HWl = 950;   Wl = 38;  Hl = 25;  }
        s_b[tid] = bq; s_lvl[tid] = lvl; s_hw[tid] = hw; s_HW[tid] = HWl;
        int hh = hw / Wl, ww = hw - hh * Wl;
        float x = -1.0f + 2.0f * (float)ww / (float)(Wl - 1);
        float y = -1.0f + 2.0f * (float)hh / (float)(Hl - 1);
        float sv = scores[bq * NTOK + idx];
        float sp = 1.0f / (1.0f + expf(-sv));
        q[tid][512] = x; q[tid][513] = y; q[tid][514] = sp;
        q[tid][515] = 0.0f; q[tid][516] = 0.0f; q[tid][517] = 0.0f;
        q[tid][518] = 0.0f; q[tid][519] = 0.0f;
    }
    __syncthreads();
    #pragma unroll
    for (int j = tid; j < QT * 256; j += 512) {
        const int t = j >> 8, c = j & 255;
        const int lvl = s_lvl[t];
        const float* f = (lvl == 0) ? f0 : ((lvl == 1) ? f1 : f2);
        q[t][c]       = f[((size_t)(s_b[t] * 256 + c)) * s_HW[t] + s_hw[t]];
        q[t][256 + c] = level_emb[lvl * 256 + c];
    }
    __syncthreads();

    float acc[QT];

    // ---- layer 1
    {
        #pragma unroll
        for (int t = 0; t < QT; ++t) acc[t] = 0.0f;
        const float* wp = w1 + (size_t)(kh * 256) * 256 + out;
        float a0 = wp[0], a1 = wp[256], a2 = wp[512], a3 = wp[768];
        for (int i4 = 0; i4 < 64; ++i4) {
            float c0 = a0, c1 = a1, c2 = a2, c3 = a3;
            const float* wn = wp + 1024;
            if (i4 < 63) { a0 = wn[0]; a1 = wn[256]; a2 = wn[512]; a3 = wn[768]; }
            wp = wn;
            const int kb = kh * 256 + i4 * 4;
            #pragma unroll
            for (int t = 0; t < QT; ++t) {
                float4 qv = *reinterpret_cast<const float4*>(&q[t][kb]);
                acc[t] += qv.x * c0 + qv.y * c1 + qv.z * c2 + qv.w * c3;
            }
        }
        if (kh) {
            for (int r = 512; r < 515; ++r) {
                float wv = w1[(size_t)r * 256 + out];
                #pragma unroll
                for (int t = 0; t < QT; ++t) acc[t] += q[t][r] * wv;
            }
            #pragma unroll
            for (int t = 0; t < QT; ++t) part[t][out] = acc[t];
        }
    }
    __syncthreads();
    if (kh == 0) {
        float bj = b1[out];
        #pragma unroll
        for (int t = 0; t < QT; ++t) h[t][out] = fmaxf(acc[t] + part[t][out] + bj, 0.0f);
    }
    __syncthreads();

    // ---- layer 2
    {
        #pragma unroll
        for (int t = 0; t < QT; ++t) acc[t] = 0.0f;
        const float* wp = w2 + (size_t)(kh * 128) * 256 + out;
        float a0 = wp[0], a1 = wp[256], a2 = wp[512], a3 = wp[768];
        for (int i4 = 0; i4 < 32; ++i4) {
            float c0 = a0, c1 = a1, c2 = a2, c3 = a3;
            const float* wn = wp + 1024;
            if (i4 < 31) { a0 = wn[0]; a1 = wn[256]; a2 = wn[512]; a3 = wn[768]; }
            wp = wn;
            const int kb = kh * 128 + i4 * 4;
            #pragma unroll
            for (int t = 0; t < QT; ++t) {
                float4 hv = *reinterpret_cast<const float4*>(&h[t][kb]);
                acc[t] += hv.x * c0 + hv.y * c1 + hv.z * c2 + hv.w * c3;
            }
        }
        if (kh) {
            #pragma unroll
            for (int t = 0; t < QT; ++t) part[t][out] = acc[t];
        }
    }
    __syncthreads();
    if (kh == 0) {
        float bj = b2[out];
        #pragma unroll
        for (int t = 0; t < QT; ++t) q[t][out] = fmaxf(acc[t] + part[t][out] + bj, 0.0f);
    }
    __syncthreads();

    // ---- gate
    if (tid < 256) {
        const int t = tid >> 5, seg = tid & 31;
        float l0 = 0.f, l1 = 0.f, l2 = 0.f;
        for (int c = seg * 8; c < seg * 8 + 8; ++c) {
            float hv = q[t][c];
            l0 += hv * gate_w[c * 8 + 0];
            l1 += hv * gate_w[c * 8 + 1];
            l2 += hv * gate_w[c * 8 + 2];
        }
        float* gp = &part[0][0];
        gp[(t * 32 + seg) * 3 + 0] = l0;
        gp[(t * 32 + seg) * 3 + 1] = l1;
        gp[(t * 32 + seg) * 3 + 2] = l2;
    }
    __syncthreads();
    if (tid < QT) {
        const int t = tid;
        float l0 = gate_b[0], l1 = gate_b[1], l2 = gate_b[2];
        const float* gp = &part[0][0];
        for (int seg = 0; seg < 32; ++seg) {
            l0 += gp[(t * 32 + seg) * 3 + 0];
            l1 += gp[(t * 32 + seg) * 3 + 1];
            l2 += gp[(t * 32 + seg) * 3 + 2];
        }
        float m = fmaxf(l0, fmaxf(l1, l2));
        float e0 = expf(l0 - m), e1 = expf(l1 - m), e2 = expf(l2 - m);
        float inv = 1.0f / (e0 + e1 + e2);
        G[(k0 + t) * 3 + 0] = e0 * inv;
        G[(k0 + t) * 3 + 1] = e1 * inv;
        G[(k0 + t) * 3 + 2] = e2 * inv;
    }
}

// ---------------- K4: scale reduce + NT streaming multiply (contiguous chunks) ----------------
__global__ __launch_bounds__(256) void out_kernel(
    const f32x4* __restrict__ f0, const f32x4* __restrict__ f1, const f32x4* __restrict__ f2,
    const float* __restrict__ G, const float* __restrict__ rs, f32x4* __restrict__ out)
{
    __shared__ float red[3][32];
    __shared__ float ssc[3];
    const int b = blockIdx.y;
    const int tid = threadIdx.x;
    if (tid < 96) {
        const int l = tid / 32, c = tid % 32;
        float s = 0.0f;
        const int kb = c * 10;
        const int ke = (kb + 10 < KTOP) ? kb + 10 : KTOP;
        for (int k = kb; k < ke; ++k) s += G[(size_t)(b * KTOP + k) * 3 + l];
        red[l][c] = s;
    }
    __syncthreads();
    for (int off = 16; off > 0; off >>= 1) {
        if (tid < 96) {
            const int l = tid / 32, c = tid % 32;
            if (c < off) red[l][c] += red[l][c + off];
        }
        __syncthreads();
    }
    if (tid < 3) ssc[tid] = 1.0f + rs[0] * (red[tid][0] / (float)KTOP);
    __syncthreads();

    const int bx = blockIdx.x;                 // 0..255
    f32x4* ob = out + (size_t)b * 1276800;
    {   // level 0
        const float sc = ssc[0];
        const f32x4* src = f0 + (size_t)b * 972800 + bx * 3800;
        f32x4* dst = ob + bx * 3800;
        #pragma unroll 4
        for (int r = tid; r < 3800; r += 256)
            __builtin_nontemporal_store(src[r] * sc, &dst[r]);
    }
    {   // level 1
        const float sc = ssc[1];
        const f32x4* src = f1 + (size_t)b * 243200 + bx * 950;
        f32x4* dst = ob + 972800 + bx * 950;
        #pragma unroll 4
        for (int r = tid; r < 950; r += 256)
            __builtin_nontemporal_store(src[r] * sc, &dst[r]);
    }
    {   // level 2
        const float sc = ssc[2];
        const int base = bx * 238;
        const int lim = (base + 238 < 60800) ? 238 : (60800 - base);
        const f32x4* src = f2 + (size_t)b * 60800 + base;
        f32x4* dst = ob + 1216000 + base;
        #pragma unroll 2
        for (int r = tid; r < lim; r += 256)
            __builtin_nontemporal_store(src[r] * sc, &dst[r]);
    }
}

extern "C" void kernel_launch(void* const* d_in, const int* in_sizes, int n_in,
                              void* d_out, int out_size, void* d_ws, size_t ws_size,
                              hipStream_t stream)
{
    const float* f0        = (const float*)d_in[0];
    const float* f1        = (const float*)d_in[1];
    const float* f2        = (const float*)d_in[2];
    const float* conv_w    = (const float*)d_in[3];
    const float* conv_b    = (const float*)d_in[4];
    const float* level_emb = (const float*)d_in[5];
    const float* w1        = (const float*)d_in[6];
    const float* b1        = (const float*)d_in[7];
    const float* w2        = (const float*)d_in[8];
    const float* b2        = (const float*)d_in[9];
    const float* gate_w    = (const float*)d_in[10];
    const float* gate_b    = (const float*)d_in[11];
    const float* rs        = (const float*)d_in[12];

    char* ws = (char*)d_ws;
    float*    scores  = (float*)ws;                    // 638.4 KB
    int*      top_idx = (int*)(ws + 640 * 1024);       // 9.6 KB
    float*    G       = (float*)(ws + 656 * 1024);     // 28.8 KB
    int*      ghist   = (int*)(ws + 688 * 1024);       // 8 KB
    int*      cnt     = (int*)(ws + 696 * 1024);       // 16 ints: gcnt[8], gccnt[8]
    uint32_t* cand_k  = (uint32_t*)(ws + 704 * 1024);  // 128 KB
    int*      cand_i  = (int*)(ws + 832 * 1024);       // 128 KB
    float*    partial = (float*)(ws + 1024 * 1024);    // 9.75 MB

    score_part_kernel<<<768, 256, 0, stream>>>(f0, f1, f2, conv_w, partial, ghist, cnt);
    score_reduce_kernel<<<dim3(78, NB), 256, 0, stream>>>(partial, conv_b, scores, ghist);
    topk_emit_kernel<<<dim3(78, NB), 256, 0, stream>>>(scores, ghist, cnt, top_idx, cand_k, cand_i);
    topk_refine_kernel<<<NB, 256, 0, stream>>>(scores, ghist, cnt, top_idx, cand_k, cand_i);
    mlp_kernel<<<NQ / QT, 512, 0, stream>>>(f0, f1, f2, scores, top_idx, level_emb,
                                            w1, b1, w2, b2, gate_w, gate_b, G);
    out_kernel<<<dim3(256, NB), 256, 0, stream>>>((const f32x4*)f0, (const f32x4*)f1,
                                                  (const f32x4*)f2, G, rs, (f32x4*)d_out);
}

// Round 15
// 214.013 us; speedup vs baseline: 1.0973x; 1.0973x over previous
//
#include <hip/hip_runtime.h>
#include <hip/hip_bf16.h>

#define NTOK 19950
#define NTOKP 19968      // padded row for partials
#define KTOP 300
#define NB 8
#define NQ 2400          // NB * KTOP
#define QDIM 520         // 515 padded to 520
#define NCC 16           // c-chunks of 16
#define CAND 4096

typedef float f32x4 __attribute__((ext_vector_type(4)));

__device__ __forceinline__ uint32_t fkey(float f) {
    uint32_t u = __float_as_uint(f);
    return (u & 0x80000000u) ? ~u : (u | 0x80000000u);
}

// suffix sums over 256 bins: hist[i] <- sum_{j>=i} hist[j]; needs hist[256]==0.
__device__ __forceinline__ void suffix_scan_256(int* hist, int tid) {
    if (tid < 64) {
        const int c0 = hist[tid * 4], c1 = hist[tid * 4 + 1];
        const int c2 = hist[tid * 4 + 2], c3 = hist[tid * 4 + 3];
        const int tot = c0 + c1 + c2 + c3;
        int s = tot;
        #pragma unroll
        for (int off = 1; off < 64; off <<= 1) {
            int o = __shfl_down(s, off);
            if (tid + off < 64) s += o;
        }
        const int Sn = s - tot;
        hist[tid * 4 + 3] = c3 + Sn;
        hist[tid * 4 + 2] = c2 + c3 + Sn;
        hist[tid * 4 + 1] = c1 + c2 + c3 + Sn;
        hist[tid * 4 + 0] = tot + Sn;
    }
}

// ---------------- K1a: partial scores, contiguous-streaming reads ----------------
__global__ __launch_bounds__(256) void score_part_kernel(
    const float* __restrict__ f0, const float* __restrict__ f1, const float* __restrict__ f2,
    const float* __restrict__ conv_w, float* __restrict__ partial, int* __restrict__ ghist,
    int* __restrict__ cnt)
{
    __shared__ float cwch[16];
    const int tid = threadIdx.x;
    const int blk = blockIdx.x;
    int b, cc;
    if (blk < 512)      { b = blk >> 6; cc = (blk >> 2) & 15; }
    else if (blk < 640) { int i = blk - 512; b = i >> 4; cc = i & 15; }
    else                { int i = blk - 640; b = i >> 4; cc = i & 15; }
    if (blk >= 640 && ((blk - 640) & 15) == 0 && tid < 256)
        ghist[((blk - 640) >> 4) * 256 + tid] = 0;
    if (blk == 640 && tid < 16) cnt[tid] = 0;          // gcnt[8] + gccnt[8]
    if (tid < 16) cwch[tid] = conv_w[cc * 16 + tid];
    __syncthreads();

    if (blk < 512) {                       // f0: quarter q -> 950 f32x4 tile
        const int q = blk & 3;
        const f32x4* b4 = (const f32x4*)(f0 + ((size_t)(b * 256 + cc * 16)) * 15200) + q * 950;
        const int s3 = (tid + 768 < 950) ? tid + 768 : 0;
        f32x4 a0 = {0,0,0,0}, a1 = a0, a2 = a0, a3 = a0;
        #pragma unroll 4
        for (int c = 0; c < 16; ++c) {
            const f32x4* r = b4 + (size_t)c * 3800;
            const float w = cwch[c];
            f32x4 v0 = r[tid], v1 = r[tid + 256], v2 = r[tid + 512], v3 = r[s3];
            a0 += v0 * w; a1 += v1 * w; a2 += v2 * w; a3 += v3 * w;
        }
        f32x4* o4 = (f32x4*)(partial + (size_t)(cc * NB + b) * NTOKP) + q * 950;
        o4[tid] = a0; o4[tid + 256] = a1; o4[tid + 512] = a2;
        if (tid + 768 < 950) o4[tid + 768] = a3;
    } else if (blk < 640) {                // f1
        const f32x4* b4 = (const f32x4*)(f1 + ((size_t)(b * 256 + cc * 16)) * 3800);
        const int s3 = (tid + 768 < 950) ? tid + 768 : 0;
        f32x4 a0 = {0,0,0,0}, a1 = a0, a2 = a0, a3 = a0;
        #pragma unroll 4
        for (int c = 0; c < 16; ++c) {
            const f32x4* r = b4 + (size_t)c * 950;
            const float w = cwch[c];
            f32x4 v0 = r[tid], v1 = r[tid + 256], v2 = r[tid + 512], v3 = r[s3];
            a0 += v0 * w; a1 += v1 * w; a2 += v2 * w; a3 += v3 * w;
        }
        f32x4* o4 = (f32x4*)(partial + (size_t)(cc * NB + b) * NTOKP + 15200);
        o4[tid] = a0; o4[tid + 256] = a1; o4[tid + 512] = a2;
        if (tid + 768 < 950) o4[tid + 768] = a3;
    } else {                               // f2
        const float2* b2 = (const float2*)(f2 + ((size_t)(b * 256 + cc * 16)) * 950);
        const int s1 = (tid + 256 < 475) ? tid + 256 : 0;
        float2 a0 = {0,0}, a1 = a0;
        #pragma unroll 4
        for (int c = 0; c < 16; ++c) {
            const float2* r = b2 + (size_t)c * 475;
            const float w = cwch[c];
            float2 v0 = r[tid], v1 = r[s1];
            a0.x += v0.x * w; a0.y += v0.y * w;
            a1.x += v1.x * w; a1.y += v1.y * w;
        }
        float2* o2 = (float2*)(partial + (size_t)(cc * NB + b) * NTOKP + 19000);
        if (tid < 475) o2[tid] = a0;
        if (tid + 256 < 475) o2[tid + 256] = a1;
    }
}

// ---------------- K1b: reduce partials + per-batch top-byte histogram ----------------
__global__ __launch_bounds__(256) void score_reduce_kernel(
    const float* __restrict__ partial, const float* __restrict__ conv_b,
    float* __restrict__ scores, int* __restrict__ ghist)
{
    __shared__ int lh[256];
    const int tid = threadIdx.x;
    const int b = blockIdx.y;
    const int i = blockIdx.x * 256 + tid;
    lh[tid] = 0;
    __syncthreads();
    if (i < NTOK) {
        float s = 0.0f;
        #pragma unroll
        for (int cc = 0; cc < NCC; ++cc)
            s += partial[(size_t)(cc * NB + b) * NTOKP + i];
        s += conv_b[0];
        scores[b * NTOK + i] = s;
        atomicAdd(&lh[fkey(s) >> 24], 1);
    }
    __syncthreads();
    if (lh[tid]) atomicAdd(&ghist[b * 256 + tid], lh[tid]);
}

// ---------------- K2a: parallel emit, block-aggregated (2 global atomics/block) ------
__global__ __launch_bounds__(256) void topk_emit_kernel(
    const float* __restrict__ scores, const int* __restrict__ ghist,
    int* __restrict__ cnt, int* __restrict__ top_idx,
    uint32_t* __restrict__ cand_k, int* __restrict__ cand_i)
{
    __shared__ int sfx[257];
    __shared__ int s_v;
    __shared__ int sel_loc[256];
    __shared__ uint32_t ck_loc[256];
    __shared__ int ci_loc[256];
    __shared__ int nsel, ncand, base_sel, base_cand;
    const int tid = threadIdx.x;
    const int b = blockIdx.y;
    const int i = blockIdx.x * 256 + tid;
    sfx[tid] = ghist[b * 256 + tid];
    if (tid == 0) { sfx[256] = 0; nsel = 0; ncand = 0; }
    __syncthreads();
    suffix_scan_256(sfx, tid);
    __syncthreads();
    if (sfx[tid] >= KTOP && sfx[tid + 1] < KTOP) s_v = tid;
    __syncthreads();
    const uint32_t v = (uint32_t)s_v;
    if (i < NTOK) {
        uint32_t k = fkey(scores[b * NTOK + i]);
        uint32_t tb = k >> 24;
        if (tb > v) {
            int p = atomicAdd(&nsel, 1);
            sel_loc[p] = i;
        } else if (tb == v) {
            int p = atomicAdd(&ncand, 1);
            ck_loc[p] = k; ci_loc[p] = i;
        }
    }
    __syncthreads();
    if (tid == 0) {
        base_sel  = (nsel  > 0) ? atomicAdd(&cnt[b], nsel)      : 0;
        base_cand = (ncand > 0) ? atomicAdd(&cnt[8 + b], ncand) : 0;
    }
    __syncthreads();
    if (tid < nsel)  top_idx[b * KTOP + base_sel + tid] = sel_loc[tid];
    if (tid < ncand) {
        int p = base_cand + tid;
        if (p < CAND) { cand_k[b * CAND + p] = ck_loc[tid]; cand_i[b * CAND + p] = ci_loc[tid]; }
    }
}

// ---------------- K2b: refine boundary bucket (8 small blocks) ----------------
__global__ __launch_bounds__(256, 1) void topk_refine_kernel(
    const float* __restrict__ scores, const int* __restrict__ ghist,
    const int* __restrict__ cnt, int* __restrict__ top_idx,
    const uint32_t* __restrict__ cand_k, const int* __restrict__ cand_i)
{
    __shared__ int hist[257];
    __shared__ uint32_t ck[CAND];
    __shared__ int ci[CAND];
    __shared__ int tie[1024];
    __shared__ uint32_t s_prefix;
    __shared__ int s_Kr, s_cnt, s_tcnt;
    const int tid = threadIdx.x;
    const int b = blockIdx.x;

    hist[tid] = ghist[b * 256 + tid];
    if (tid == 0) { hist[256] = 0; s_tcnt = 0; }
    __syncthreads();
    suffix_scan_256(hist, tid);
    __syncthreads();
    if (hist[tid] >= KTOP && hist[tid + 1] < KTOP) {
        s_prefix = (uint32_t)tid << 24;
        s_Kr = KTOP - hist[tid + 1];
        s_cnt = hist[tid + 1];             // sure-selected count already emitted
    }
    __syncthreads();
    const uint32_t v = s_prefix >> 24;
    const int ccnt = cnt[8 + b];
    const bool fits = (ccnt <= CAND);
    const int ncand = fits ? ccnt : CAND;
    if (fits)
        for (int j = tid; j < ncand; j += 256) { ck[j] = cand_k[b * CAND + j]; ci[j] = cand_i[b * CAND + j]; }
    __syncthreads();

    uint32_t pmask = 0xFF000000u;
    for (int pass = 1; pass < 4; ++pass) {
        const int shift = 24 - 8 * pass;
        hist[tid] = 0;
        if (tid == 0) hist[256] = 0;
        __syncthreads();
        const uint32_t prefix = s_prefix;
        const int Kr = s_Kr;
        if (fits) {
            for (int j = tid; j < ncand; j += 256) {
                uint32_t k = ck[j];
                if ((k & pmask) == prefix) atomicAdd(&hist[(k >> shift) & 255], 1);
            }
        } else {
            for (int i = tid; i < NTOK; i += 256) {
                uint32_t k = fkey(scores[b * NTOK + i]);
                if ((k & pmask) == prefix) atomicAdd(&hist[(k >> shift) & 255], 1);
            }
        }
        __syncthreads();
        suffix_scan_256(hist, tid);
        __syncthreads();
        if (hist[tid] >= Kr && hist[tid + 1] < Kr) {
            s_prefix = prefix | ((uint32_t)tid << shift);
            s_Kr = Kr - hist[tid + 1];
        }
        __syncthreads();
        pmask |= (0xFFu << shift);
    }
    const uint32_t T = s_prefix;
    const int need = s_Kr;

    if (fits) {
        for (int j = tid; j < ncand; j += 256) {
            uint32_t k = ck[j];
            if (k > T) {
                int p = atomicAdd(&s_cnt, 1);
                top_idx[b * KTOP + p] = ci[j];
            } else if (k == T) {
                int p = atomicAdd(&s_tcnt, 1);
                if (p < 1024) tie[p] = ci[j];
            }
        }
    } else {
        for (int i = tid; i < NTOK; i += 256) {
            uint32_t k = fkey(scores[b * NTOK + i]);
            if ((k >> 24) == v) {
                if (k > T) {
                    int p = atomicAdd(&s_cnt, 1);
                    top_idx[b * KTOP + p] = i;
                } else if (k == T) {
                    int p = atomicAdd(&s_tcnt, 1);
                    if (p < 1024) tie[p] = i;
                }
            }
        }
    }
    __syncthreads();
    if (tid == 0) {
        const int base = KTOP - need;      // ties fill the tail deterministically
        int tcnt = s_tcnt > 1024 ? 1024 : s_tcnt;
        for (int s = 0; s < need; ++s) {   // 'need' smallest tie indices
            int mi = s;
            for (int u = s + 1; u < tcnt; ++u) if (tie[u] < tie[mi]) mi = u;
            int tmp = tie[s]; tie[s] = tie[mi]; tie[mi] = tmp;
            top_idx[b * KTOP + base + s] = tie[s];
        }
    }
}

// ---------------- K3: gather (fused) + MLP -> per-query gates G[2400][3] ----------------
#define QT 8
__global__ __launch_bounds__(512, 1) void mlp_kernel(
    const float* __restrict__ f0, const float* __restrict__ f1, const float* __restrict__ f2,
    const float* __restrict__ scores, const int* __restrict__ top_idx,
    const float* __restrict__ level_emb,
    const float* __restrict__ w1, const float* __restrict__ b1,
    const float* __restrict__ w2, const float* __restrict__ b2,
    const float* __restrict__ gate_w, const float* __restrict__ gate_b,
    float* __restrict__ G)
{
    __shared__ __align__(16) float q[QT][QDIM];
    __shared__ __align__(16) float part[QT][256];
    __shared__ __align__(16) float h[QT][256];
    __shared__ int s_b[QT], s_lvl[QT], s_hw[QT], s_HW[QT];
    const int tid = threadIdx.x;
    const int out = tid & 255;
    const int kh = tid >> 8;
    const int k0 = blockIdx.x * QT;

    if (tid < QT) {
        const int kk = k0 + tid;
        const int bq = kk / KTOP;
        const int idx = top_idx[kk];
        int lvl, hw, HWl, Wl, Hl;
        if (idx < 15200)      { lvl = 0; hw = idx;         HWl = 15200; Wl = 152; Hl = 100; }
        else if (idx < 19000) { lvl = 1; hw = idx - 15200; HWl = 3800;  Wl = 76;  Hl = 50;  }
        else                  { lvl = 2; hw = idx - 19000; HWl = 950;   Wl = 38;  Hl = 25;  }
        s_b[tid] = bq; s_lvl[tid] = lvl; s_hw[tid] = hw; s_HW[tid] = HWl;
        int hh = hw / Wl, ww = hw - hh * Wl;
        float x = -1.0f + 2.0f * (float)ww / (float)(Wl - 1);
        float y = -1.0f + 2.0f * (float)hh / (float)(Hl - 1);
        float sv = scores[bq * NTOK + idx];
        float sp = 1.0f / (1.0f + expf(-sv));
        q[tid][512] = x; q[tid][513] = y; q[tid][514] = sp;
        q[tid][515] = 0.0f; q[tid][516] = 0.0f; q[tid][517] = 0.0f;
        q[tid][518] = 0.0f; q[tid][519] = 0.0f;
    }
    __syncthreads();
    #pragma unroll
    for (int j = tid; j < QT * 256; j += 512) {
        const int t = j >> 8, c = j & 255;
        const int lvl = s_lvl[t];
        const float* f = (lvl == 0) ? f0 : ((lvl == 1) ? f1 : f2);
        q[t][c]       = f[((size_t)(s_b[t] * 256 + c)) * s_HW[t] + s_hw[t]];
        q[t][256 + c] = level_emb[lvl * 256 + c];
    }
    __syncthreads();

    float acc[QT];

    // ---- layer 1
    {
        #pragma unroll
        for (int t = 0; t < QT; ++t) acc[t] = 0.0f;
        const float* wp = w1 + (size_t)(kh * 256) * 256 + out;
        float a0 = wp[0], a1 = wp[256], a2 = wp[512], a3 = wp[768];
        for (int i4 = 0; i4 < 64; ++i4) {
            float c0 = a0, c1 = a1, c2 = a2, c3 = a3;
            const float* wn = wp + 1024;
            if (i4 < 63) { a0 = wn[0]; a1 = wn[256]; a2 = wn[512]; a3 = wn[768]; }
            wp = wn;
            const int kb = kh * 256 + i4 * 4;
            #pragma unroll
            for (int t = 0; t < QT; ++t) {
                float4 qv = *reinterpret_cast<const float4*>(&q[t][kb]);
                acc[t] += qv.x * c0 + qv.y * c1 + qv.z * c2 + qv.w * c3;
            }
        }
        if (kh) {
            for (int r = 512; r < 515; ++r) {
                float wv = w1[(size_t)r * 256 + out];
                #pragma unroll
                for (int t = 0; t < QT; ++t) acc[t] += q[t][r] * wv;
            }
            #pragma unroll
            for (int t = 0; t < QT; ++t) part[t][out] = acc[t];
        }
    }
    __syncthreads();
    if (kh == 0) {
        float bj = b1[out];
        #pragma unroll
        for (int t = 0; t < QT; ++t) h[t][out] = fmaxf(acc[t] + part[t][out] + bj, 0.0f);
    }
    __syncthreads();

    // ---- layer 2
    {
        #pragma unroll
        for (int t = 0; t < QT; ++t) acc[t] = 0.0f;
        const float* wp = w2 + (size_t)(kh * 128) * 256 + out;
        float a0 = wp[0], a1 = wp[256], a2 = wp[512], a3 = wp[768];
        for (int i4 = 0; i4 < 32; ++i4) {
            float c0 = a0, c1 = a1, c2 = a2, c3 = a3;
            const float* wn = wp + 1024;
            if (i4 < 31) { a0 = wn[0]; a1 = wn[256]; a2 = wn[512]; a3 = wn[768]; }
            wp = wn;
            const int kb = kh * 128 + i4 * 4;
            #pragma unroll
            for (int t = 0; t < QT; ++t) {
                float4 hv = *reinterpret_cast<const float4*>(&h[t][kb]);
                acc[t] += hv.x * c0 + hv.y * c1 + hv.z * c2 + hv.w * c3;
            }
        }
        if (kh) {
            #pragma unroll
            for (int t = 0; t < QT; ++t) part[t][out] = acc[t];
        }
    }
    __syncthreads();
    if (kh == 0) {
        float bj = b2[out];
        #pragma unroll
        for (int t = 0; t < QT; ++t) q[t][out] = fmaxf(acc[t] + part[t][out] + bj, 0.0f);
    }
    __syncthreads();

    // ---- gate
    if (tid < 256) {
        const int t = tid >> 5, seg = tid & 31;
        float l0 = 0.f, l1 = 0.f, l2 = 0.f;
        for (int c = seg * 8; c < seg * 8 + 8; ++c) {
            float hv = q[t][c];
            l0 += hv * gate_w[c * 8 + 0];
            l1 += hv * gate_w[c * 8 + 1];
            l2 += hv * gate_w[c * 8 + 2];
        }
        float* gp = &part[0][0];
        gp[(t * 32 + seg) * 3 + 0] = l0;
        gp[(t * 32 + seg) * 3 + 1] = l1;
        gp[(t * 32 + seg) * 3 + 2] = l2;
    }
    __syncthreads();
    if (tid < QT) {
        const int t = tid;
        float l0 = gate_b[0], l1 = gate_b[1], l2 = gate_b[2];
        const float* gp = &part[0][0];
        for (int seg = 0; seg < 32; ++seg) {
            l0 += gp[(t * 32 + seg) * 3 + 0];
            l1 += gp[(t * 32 + seg) * 3 + 1];
            l2 += gp[(t * 32 + seg) * 3 + 2];
        }
        float m = fmaxf(l0, fmaxf(l1, l2));
        float e0 = expf(l0 - m), e1 = expf(l1 - m), e2 = expf(l2 - m);
        float inv = 1.0f / (e0 + e1 + e2);
        G[(k0 + t) * 3 + 0] = e0 * inv;
        G[(k0 + t) * 3 + 1] = e1 * inv;
        G[(k0 + t) * 3 + 2] = e2 * inv;
    }
}

// ---------------- K4: scale reduce + NT streaming multiply (contiguous chunks) ----------------
__global__ __launch_bounds__(256) void out_kernel(
    const f32x4* __restrict__ f0, const f32x4* __restrict__ f1, const f32x4* __restrict__ f2,
    const float* __restrict__ G, const float* __restrict__ rs, f32x4* __restrict__ out)
{
    __shared__ float red[3][32];
    __shared__ float ssc[3];
    const int b = blockIdx.y;
    const int tid = threadIdx.x;
    if (tid < 96) {
        const int l = tid / 32, c = tid % 32;
        float s = 0.0f;
        const int kb = c * 10;
        const int ke = (kb + 10 < KTOP) ? kb + 10 : KTOP;
        for (int k = kb; k < ke; ++k) s += G[(size_t)(b * KTOP + k) * 3 + l];
        red[l][c] = s;
    }
    __syncthreads();
    for (int off = 16; off > 0; off >>= 1) {
        if (tid < 96) {
            const int l = tid / 32, c = tid % 32;
            if (c < off) red[l][c] += red[l][c + off];
        }
        __syncthreads();
    }
    if (tid < 3) ssc[tid] = 1.0f + rs[0] * (red[tid][0] / (float)KTOP);
    __syncthreads();

    const int bx = blockIdx.x;                 // 0..255
    f32x4* ob = out + (size_t)b * 1276800;
    {   // level 0
        const float sc = ssc[0];
        const f32x4* src = f0 + (size_t)b * 972800 + bx * 3800;
        f32x4* dst = ob + bx * 3800;
        #pragma unroll 4
        for (int r = tid; r < 3800; r += 256)
            __builtin_nontemporal_store(src[r] * sc, &dst[r]);
    }
    {   // level 1
        const float sc = ssc[1];
        const f32x4* src = f1 + (size_t)b * 243200 + bx * 950;
        f32x4* dst = ob + 972800 + bx * 950;
        #pragma unroll 4
        for (int r = tid; r < 950; r += 256)
            __builtin_nontemporal_store(src[r] * sc, &dst[r]);
    }
    {   // level 2
        const float sc = ssc[2];
        const int base = bx * 238;
        const int lim = (base + 238 < 60800) ? 238 : (60800 - base);
        const f32x4* src = f2 + (size_t)b * 60800 + base;
        f32x4* dst = ob + 1216000 + base;
        #pragma unroll 2
        for (int r = tid; r < lim; r += 256)
            __builtin_nontemporal_store(src[r] * sc, &dst[r]);
    }
}

extern "C" void kernel_launch(void* const* d_in, const int* in_sizes, int n_in,
                              void* d_out, int out_size, void* d_ws, size_t ws_size,
                              hipStream_t stream)
{
    const float* f0        = (const float*)d_in[0];
    const float* f1        = (const float*)d_in[1];
    const float* f2        = (const float*)d_in[2];
    const float* conv_w    = (const float*)d_in[3];
    const float* conv_b    = (const float*)d_in[4];
    const float* level_emb = (const float*)d_in[5];
    const float* w1        = (const float*)d_in[6];
    const float* b1        = (const float*)d_in[7];
    const float* w2        = (const float*)d_in[8];
    const float* b2        = (const float*)d_in[9];
    const float* gate_w    = (const float*)d_in[10];
    const float* gate_b    = (const float*)d_in[11];
    const float* rs        = (const float*)d_in[12];

    char* ws = (char*)d_ws;
    float*    scores  = (float*)ws;                    // 638.4 KB
    int*      top_idx = (int*)(ws + 640 * 1024);       // 9.6 KB
    float*    G       = (float*)(ws + 656 * 1024);     // 28.8 KB
    int*      ghist   = (int*)(ws + 688 * 1024);       // 8 KB
    int*      cnt     = (int*)(ws + 696 * 1024);       // 16 ints: gcnt[8], gccnt[8]
    uint32_t* cand_k  = (uint32_t*)(ws + 704 * 1024);  // 128 KB
    int*      cand_i  = (int*)(ws + 832 * 1024);       // 128 KB
    float*    partial = (float*)(ws + 1024 * 1024);    // 9.75 MB

    score_part_kernel<<<768, 256, 0, stream>>>(f0, f1, f2, conv_w, partial, ghist, cnt);
    score_reduce_kernel<<<dim3(78, NB), 256, 0, stream>>>(partial, conv_b, scores, ghist);
    topk_emit_kernel<<<dim3(78, NB), 256, 0, stream>>>(scores, ghist, cnt, top_idx, cand_k, cand_i);
    topk_refine_kernel<<<NB, 256, 0, stream>>>(scores, ghist, cnt, top_idx, cand_k, cand_i);
    mlp_kernel<<<NQ / QT, 512, 0, stream>>>(f0, f1, f2, scores, top_idx, level_emb,
                                            w1, b1, w2, b2, gate_w, gate_b, G);
    out_kernel<<<dim3(256, NB), 256, 0, stream>>>((const f32x4*)f0, (const f32x4*)f1,
                                                  (const f32x4*)f2, G, rs, (f32x4*)d_out);
}

// Round 16
// 150.031 us; speedup vs baseline: 1.5653x; 1.4265x over previous
//
#include <hip/hip_runtime.h>
#include <hip/hip_bf16.h>

#define NTOK 19950
#define NTOKP 19968      // padded row for partials
#define KTOP 300
#define NB 8
#define NQ 2400          // NB * KTOP
#define QDIM 520         // 515 padded to 520
#define NCC 16           // c-chunks of 16

typedef float f32x4 __attribute__((ext_vector_type(4)));

__device__ __forceinline__ uint32_t fkey(float f) {
    uint32_t u = __float_as_uint(f);
    return (u & 0x80000000u) ? ~u : (u | 0x80000000u);
}

// ---------------- K1a: partial scores, contiguous-streaming reads ----------------
__global__ __launch_bounds__(256) void score_part_kernel(
    const float* __restrict__ f0, const float* __restrict__ f1, const float* __restrict__ f2,
    const float* __restrict__ conv_w, float* __restrict__ partial, int* __restrict__ ghist)
{
    __shared__ float cwch[16];
    const int tid = threadIdx.x;
    const int blk = blockIdx.x;
    int b, cc;
    if (blk < 512)      { b = blk >> 6; cc = (blk >> 2) & 15; }
    else if (blk < 640) { int i = blk - 512; b = i >> 4; cc = i & 15; }
    else                { int i = blk - 640; b = i >> 4; cc = i & 15; }
    if (blk >= 640 && ((blk - 640) & 15) == 0 && tid < 256)
        ghist[((blk - 640) >> 4) * 256 + tid] = 0;
    if (tid < 16) cwch[tid] = conv_w[cc * 16 + tid];
    __syncthreads();

    if (blk < 512) {                       // f0: quarter q -> 950 f32x4 tile
        const int q = blk & 3;
        const f32x4* b4 = (const f32x4*)(f0 + ((size_t)(b * 256 + cc * 16)) * 15200) + q * 950;
        const int s3 = (tid + 768 < 950) ? tid + 768 : 0;
        f32x4 a0 = {0,0,0,0}, a1 = a0, a2 = a0, a3 = a0;
        #pragma unroll 4
        for (int c = 0; c < 16; ++c) {
            const f32x4* r = b4 + (size_t)c * 3800;
            const float w = cwch[c];
            f32x4 v0 = r[tid], v1 = r[tid + 256], v2 = r[tid + 512], v3 = r[s3];
            a0 += v0 * w; a1 += v1 * w; a2 += v2 * w; a3 += v3 * w;
        }
        f32x4* o4 = (f32x4*)(partial + (size_t)(cc * NB + b) * NTOKP) + q * 950;
        o4[tid] = a0; o4[tid + 256] = a1; o4[tid + 512] = a2;
        if (tid + 768 < 950) o4[tid + 768] = a3;
    } else if (blk < 640) {                // f1
        const f32x4* b4 = (const f32x4*)(f1 + ((size_t)(b * 256 + cc * 16)) * 3800);
        const int s3 = (tid + 768 < 950) ? tid + 768 : 0;
        f32x4 a0 = {0,0,0,0}, a1 = a0, a2 = a0, a3 = a0;
        #pragma unroll 4
        for (int c = 0; c < 16; ++c) {
            const f32x4* r = b4 + (size_t)c * 950;
            const float w = cwch[c];
            f32x4 v0 = r[tid], v1 = r[tid + 256], v2 = r[tid + 512], v3 = r[s3];
            a0 += v0 * w; a1 += v1 * w; a2 += v2 * w; a3 += v3 * w;
        }
        f32x4* o4 = (f32x4*)(partial + (size_t)(cc * NB + b) * NTOKP + 15200);
        o4[tid] = a0; o4[tid + 256] = a1; o4[tid + 512] = a2;
        if (tid + 768 < 950) o4[tid + 768] = a3;
    } else {                               // f2
        const float2* b2 = (const float2*)(f2 + ((size_t)(b * 256 + cc * 16)) * 950);
        const int s1 = (tid + 256 < 475) ? tid + 256 : 0;
        float2 a0 = {0,0}, a1 = a0;
        #pragma unroll 4
        for (int c = 0; c < 16; ++c) {
            const float2* r = b2 + (size_t)c * 475;
            const float w = cwch[c];
            float2 v0 = r[tid], v1 = r[s1];
            a0.x += v0.x * w; a0.y += v0.y * w;
            a1.x += v1.x * w; a1.y += v1.y * w;
        }
        float2* o2 = (float2*)(partial + (size_t)(cc * NB + b) * NTOKP + 19000);
        if (tid < 475) o2[tid] = a0;
        if (tid + 256 < 475) o2[tid + 256] = a1;
    }
}

// ---------------- K1b: reduce partials + per-batch top-byte histogram ----------------
__global__ __launch_bounds__(256) void score_reduce_kernel(
    const float* __restrict__ partial, const float* __restrict__ conv_b,
    float* __restrict__ scores, int* __restrict__ ghist)
{
    __shared__ int lh[256];
    const int tid = threadIdx.x;
    const int b = blockIdx.y;
    const int i = blockIdx.x * 256 + tid;
    lh[tid] = 0;
    __syncthreads();
    if (i < NTOK) {
        float s = 0.0f;
        #pragma unroll
        for (int cc = 0; cc < NCC; ++cc)
            s += partial[(size_t)(cc * NB + b) * NTOKP + i];
        s += conv_b[0];
        scores[b * NTOK + i] = s;
        atomicAdd(&lh[fkey(s) >> 24], 1);
    }
    __syncthreads();
    if (lh[tid]) atomicAdd(&ghist[b * 256 + tid], lh[tid]);
}

// ---------------- K2: exact top-K; pass 1 from precomputed ghist ----------------
__global__ __launch_bounds__(1024, 1) void topk_kernel(
    const float* __restrict__ scores, const int* __restrict__ ghist,
    int* __restrict__ top_idx)
{
    __shared__ uint32_t key[NTOK];
    __shared__ int whist[16][256];
    __shared__ int suffix[257];
    __shared__ uint32_t s_prefix;
    __shared__ int s_Kr, s_cnt, s_tcnt;
    __shared__ int tie[1024];
    const int tid = threadIdx.x;
    const int wv = tid >> 6;
    const int b = blockIdx.x;
    const float* srow = scores + b * NTOK;
    for (int i = tid; i < NTOK; i += 1024) key[i] = fkey(srow[i]);
    if (tid == 0) { s_Kr = KTOP; suffix[256] = 0; }
    // ---- pass 1: bucket from ghist (no LDS atomic round)
    if (tid < 256) suffix[tid] = ghist[b * 256 + tid];
    __syncthreads();
    if (tid < 64) {
        const int c0 = suffix[tid * 4], c1 = suffix[tid * 4 + 1];
        const int c2 = suffix[tid * 4 + 2], c3 = suffix[tid * 4 + 3];
        const int tot = c0 + c1 + c2 + c3;
        int s = tot;
        #pragma unroll
        for (int off = 1; off < 64; off <<= 1) {
            int o = __shfl_down(s, off);
            if (tid + off < 64) s += o;
        }
        const int Sn = s - tot;
        suffix[tid * 4 + 3] = c3 + Sn;
        suffix[tid * 4 + 2] = c2 + c3 + Sn;
        suffix[tid * 4 + 1] = c1 + c2 + c3 + Sn;
        suffix[tid * 4 + 0] = tot + Sn;
    }
    __syncthreads();
    if (tid < 256) {
        int sgeq = suffix[tid];
        int sgt  = suffix[tid + 1];
        if (sgeq >= KTOP && sgt < KTOP) {
            s_prefix = (uint32_t)tid << 24;
            s_Kr = KTOP - sgt;
        }
    }
    __syncthreads();
    uint32_t pmask = 0xFF000000u;
    // ---- passes 2..4: histogram only prefix-matching keys (few hundred)
    for (int pass = 1; pass < 4; ++pass) {
        const int shift = 24 - 8 * pass;
        for (int i = tid; i < 16 * 256; i += 1024) ((int*)whist)[i] = 0;
        __syncthreads();
        const uint32_t prefix = s_prefix;
        const int Kr = s_Kr;
        for (int i = tid; i < NTOK; i += 1024) {
            uint32_t k = key[i];
            if ((k & pmask) == prefix) atomicAdd(&whist[wv][(k >> shift) & 255], 1);
        }
        __syncthreads();
        if (tid < 256) {
            int s = 0;
            #pragma unroll
            for (int w = 0; w < 16; ++w) s += whist[w][tid];
            suffix[tid] = s;
        }
        __syncthreads();
        if (tid < 64) {
            const int c0 = suffix[tid * 4], c1 = suffix[tid * 4 + 1];
            const int c2 = suffix[tid * 4 + 2], c3 = suffix[tid * 4 + 3];
            const int tot = c0 + c1 + c2 + c3;
            int s = tot;
            #pragma unroll
            for (int off = 1; off < 64; off <<= 1) {
                int o = __shfl_down(s, off);
                if (tid + off < 64) s += o;
            }
            const int Sn = s - tot;
            suffix[tid * 4 + 3] = c3 + Sn;
            suffix[tid * 4 + 2] = c2 + c3 + Sn;
            suffix[tid * 4 + 1] = c1 + c2 + c3 + Sn;
            suffix[tid * 4 + 0] = tot + Sn;
        }
        __syncthreads();
        if (tid < 256) {
            int sgeq = suffix[tid];
            int sgt  = suffix[tid + 1];
            if (sgeq >= Kr && sgt < Kr) {
                s_prefix = prefix | ((uint32_t)tid << shift);
                s_Kr = Kr - sgt;
            }
        }
        __syncthreads();
        pmask |= (0xFFu << shift);
    }
    const uint32_t T = s_prefix;
    const int need = s_Kr;
    if (tid == 0) { s_cnt = 0; s_tcnt = 0; }
    __syncthreads();
    for (int i = tid; i < NTOK; i += 1024) {
        uint32_t k = key[i];
        if (k > T) {
            int p = atomicAdd(&s_cnt, 1);
            top_idx[b * KTOP + p] = i;
        } else if (k == T) {
            int p = atomicAdd(&s_tcnt, 1);
            if (p < 1024) tie[p] = i;
        }
    }
    __syncthreads();
    if (tid == 0) {
        int base = s_cnt;
        int tcnt = s_tcnt > 1024 ? 1024 : s_tcnt;
        for (int s = 0; s < need; ++s) {
            int mi = s;
            for (int u = s + 1; u < tcnt; ++u) if (tie[u] < tie[mi]) mi = u;
            int tmp = tie[s]; tie[s] = tie[mi]; tie[mi] = tmp;
            top_idx[b * KTOP + base + s] = tie[s];
        }
    }
}

// ---------------- K3: gather (fused) + MLP -> per-query gates G[2400][3] ----------------
#define QT 8
__global__ __launch_bounds__(512, 1) void mlp_kernel(
    const float* __restrict__ f0, const float* __restrict__ f1, const float* __restrict__ f2,
    const float* __restrict__ scores, const int* __restrict__ top_idx,
    const float* __restrict__ level_emb,
    const float* __restrict__ w1, const float* __restrict__ b1,
    const float* __restrict__ w2, const float* __restrict__ b2,
    const float* __restrict__ gate_w, const float* __restrict__ gate_b,
    float* __restrict__ G)
{
    __shared__ __align__(16) float q[QT][QDIM];
    __shared__ __align__(16) float part[QT][256];
    __shared__ __align__(16) float h[QT][256];
    __shared__ int s_b[QT], s_lvl[QT], s_hw[QT], s_HW[QT];
    const int tid = threadIdx.x;
    const int out = tid & 255;
    const int kh = tid >> 8;
    const int k0 = blockIdx.x * QT;

    if (tid < QT) {
        const int kk = k0 + tid;
        const int bq = kk / KTOP;
        const int idx = top_idx[kk];
        int lvl, hw, HWl, Wl, Hl;
        if (idx < 15200)      { lvl = 0; hw = idx;         HWl = 15200; Wl = 152; Hl = 100; }
        else if (idx < 19000) { lvl = 1; hw = idx - 15200; HWl = 3800;  Wl = 76;  Hl = 50;  }
        else                  { lvl = 2; hw = idx - 19000; HWl = 950;   Wl = 38;  Hl = 25;  }
        s_b[tid] = bq; s_lvl[tid] = lvl; s_hw[tid] = hw; s_HW[tid] = HWl;
        int hh = hw / Wl, ww = hw - hh * Wl;
        float x = -1.0f + 2.0f * (float)ww / (float)(Wl - 1);
        float y = -1.0f + 2.0f * (float)hh / (float)(Hl - 1);
        float sv = scores[bq * NTOK + idx];
        float sp = 1.0f / (1.0f + expf(-sv));
        q[tid][512] = x; q[tid][513] = y; q[tid][514] = sp;
        q[tid][515] = 0.0f; q[tid][516] = 0.0f; q[tid][517] = 0.0f;
        q[tid][518] = 0.0f; q[tid][519] = 0.0f;
    }
    __syncthreads();
    #pragma unroll
    for (int j = tid; j < QT * 256; j += 512) {
        const int t = j >> 8, c = j & 255;
        const int lvl = s_lvl[t];
        const float* f = (lvl == 0) ? f0 : ((lvl == 1) ? f1 : f2);
        q[t][c]       = f[((size_t)(s_b[t] * 256 + c)) * s_HW[t] + s_hw[t]];
        q[t][256 + c] = level_emb[lvl * 256 + c];
    }
    __syncthreads();

    float acc[QT];

    // ---- layer 1
    {
        #pragma unroll
        for (int t = 0; t < QT; ++t) acc[t] = 0.0f;
        const float* wp = w1 + (size_t)(kh * 256) * 256 + out;
        float a0 = wp[0], a1 = wp[256], a2 = wp[512], a3 = wp[768];
        for (int i4 = 0; i4 < 64; ++i4) {
            float c0 = a0, c1 = a1, c2 = a2, c3 = a3;
            const float* wn = wp + 1024;
            if (i4 < 63) { a0 = wn[0]; a1 = wn[256]; a2 = wn[512]; a3 = wn[768]; }
            wp = wn;
            const int kb = kh * 256 + i4 * 4;
            #pragma unroll
            for (int t = 0; t < QT; ++t) {
                float4 qv = *reinterpret_cast<const float4*>(&q[t][kb]);
                acc[t] += qv.x * c0 + qv.y * c1 + qv.z * c2 + qv.w * c3;
            }
        }
        if (kh) {
            for (int r = 512; r < 515; ++r) {
                float wv = w1[(size_t)r * 256 + out];
                #pragma unroll
                for (int t = 0; t < QT; ++t) acc[t] += q[t][r] * wv;
            }
            #pragma unroll
            for (int t = 0; t < QT; ++t) part[t][out] = acc[t];
        }
    }
    __syncthreads();
    if (kh == 0) {
        float bj = b1[out];
        #pragma unroll
        for (int t = 0; t < QT; ++t) h[t][out] = fmaxf(acc[t] + part[t][out] + bj, 0.0f);
    }
    __syncthreads();

    // ---- layer 2
    {
        #pragma unroll
        for (int t = 0; t < QT; ++t) acc[t] = 0.0f;
        const float* wp = w2 + (size_t)(kh * 128) * 256 + out;
        float a0 = wp[0], a1 = wp[256], a2 = wp[512], a3 = wp[768];
        for (int i4 = 0; i4 < 32; ++i4) {
            float c0 = a0, c1 = a1, c2 = a2, c3 = a3;
            const float* wn = wp + 1024;
            if (i4 < 31) { a0 = wn[0]; a1 = wn[256]; a2 = wn[512]; a3 = wn[768]; }
            wp = wn;
            const int kb = kh * 128 + i4 * 4;
            #pragma unroll
            for (int t = 0; t < QT; ++t) {
                float4 hv = *reinterpret_cast<const float4*>(&h[t][kb]);
                acc[t] += hv.x * c0 + hv.y * c1 + hv.z * c2 + hv.w * c3;
            }
        }
        if (kh) {
            #pragma unroll
            for (int t = 0; t < QT; ++t) part[t][out] = acc[t];
        }
    }
    __syncthreads();
    if (kh == 0) {
        float bj = b2[out];
        #pragma unroll
        for (int t = 0; t < QT; ++t) q[t][out] = fmaxf(acc[t] + part[t][out] + bj, 0.0f);
    }
    __syncthreads();

    // ---- gate
    if (tid < 256) {
        const int t = tid >> 5, seg = tid & 31;
        float l0 = 0.f, l1 = 0.f, l2 = 0.f;
        for (int c = seg * 8; c < seg * 8 + 8; ++c) {
            float hv = q[t][c];
            l0 += hv * gate_w[c * 8 + 0];
            l1 += hv * gate_w[c * 8 + 1];
            l2 += hv * gate_w[c * 8 + 2];
        }
        float* gp = &part[0][0];
        gp[(t * 32 + seg) * 3 + 0] = l0;
        gp[(t * 32 + seg) * 3 + 1] = l1;
        gp[(t * 32 + seg) * 3 + 2] = l2;
    }
    __syncthreads();
    if (tid < QT) {
        const int t = tid;
        float l0 = gate_b[0], l1 = gate_b[1], l2 = gate_b[2];
        const float* gp = &part[0][0];
        for (int seg = 0; seg < 32; ++seg) {
            l0 += gp[(t * 32 + seg) * 3 + 0];
            l1 += gp[(t * 32 + seg) * 3 + 1];
            l2 += gp[(t * 32 + seg) * 3 + 2];
        }
        float m = fmaxf(l0, fmaxf(l1, l2));
        float e0 = expf(l0 - m), e1 = expf(l1 - m), e2 = expf(l2 - m);
        float inv = 1.0f / (e0 + e1 + e2);
        G[(k0 + t) * 3 + 0] = e0 * inv;
        G[(k0 + t) * 3 + 1] = e1 * inv;
        G[(k0 + t) * 3 + 2] = e2 * inv;
    }
}

// ---------------- K4: scale reduce + NT streaming multiply ----------------
__global__ __launch_bounds__(256) void out_kernel(
    const f32x4* __restrict__ f0, const f32x4* __restrict__ f1, const f32x4* __restrict__ f2,
    const float* __restrict__ G, const float* __restrict__ rs, f32x4* __restrict__ out)
{
    __shared__ float red[3][32];
    __shared__ float ssc[3];
    const int b = blockIdx.y;
    const int tid = threadIdx.x;
    if (tid < 96) {
        const int l = tid / 32, c = tid % 32;
        float s = 0.0f;
        const int kb = c * 10;
        const int ke = (kb + 10 < KTOP) ? kb + 10 : KTOP;
        for (int k = kb; k < ke; ++k) s += G[(size_t)(b * KTOP + k) * 3 + l];
        red[l][c] = s;
    }
    __syncthreads();
    for (int off = 16; off > 0; off >>= 1) {
        if (tid < 96) {
            const int l = tid / 32, c = tid % 32;
            if (c < off) red[l][c] += red[l][c + off];
        }
        __syncthreads();
    }
    if (tid < 3) ssc[tid] = 1.0f + rs[0] * (red[tid][0] / (float)KTOP);
    __syncthreads();

    const int t0 = blockIdx.x * 256 + tid;
    const int TPB = gridDim.x * 256;
    f32x4* ob = out + (size_t)b * 1276800;
    {
        const float sc = ssc[0];
        const f32x4* src = f0 + (size_t)b * 972800;
        for (int r = t0; r < 972800; r += TPB)
            __builtin_nontemporal_store(src[r] * sc, &ob[r]);
    }
    {
        const float sc = ssc[1];
        const f32x4* src = f1 + (size_t)b * 243200;
        f32x4* o1 = ob + 972800;
        for (int r = t0; r < 243200; r += TPB)
            __builtin_nontemporal_store(src[r] * sc, &o1[r]);
    }
    {
        const float sc = ssc[2];
        const f32x4* src = f2 + (size_t)b * 60800;
        f32x4* o2 = ob + 1216000;
        for (int r = t0; r < 60800; r += TPB)
            __builtin_nontemporal_store(src[r] * sc, &o2[r]);
    }
}

extern "C" void kernel_launch(void* const* d_in, const int* in_sizes, int n_in,
                              void* d_out, int out_size, void* d_ws, size_t ws_size,
                              hipStream_t stream)
{
    const float* f0        = (const float*)d_in[0];
    const float* f1        = (const float*)d_in[1];
    const float* f2        = (const float*)d_in[2];
    const float* conv_w    = (const float*)d_in[3];
    const float* conv_b    = (const float*)d_in[4];
    const float* level_emb = (const float*)d_in[5];
    const float* w1        = (const float*)d_in[6];
    const float* b1        = (const float*)d_in[7];
    const float* w2        = (const float*)d_in[8];
    const float* b2        = (const float*)d_in[9];
    const float* gate_w    = (const float*)d_in[10];
    const float* gate_b    = (const float*)d_in[11];
    const float* rs        = (const float*)d_in[12];

    char* ws = (char*)d_ws;
    float* scores  = (float*)ws;                   // 638.4 KB
    int*   top_idx = (int*)(ws + 640 * 1024);      // 9.6 KB
    float* G       = (float*)(ws + 656 * 1024);    // 28.8 KB
    int*   ghist   = (int*)(ws + 688 * 1024);      // 8 KB
    float* partial = (float*)(ws + 704 * 1024);    // 16*8*19968*4 = 9.75 MB

    score_part_kernel<<<768, 256, 0, stream>>>(f0, f1, f2, conv_w, partial, ghist);
    score_reduce_kernel<<<dim3(78, NB), 256, 0, stream>>>(partial, conv_b, scores, ghist);
    topk_kernel<<<NB, 1024, 0, stream>>>(scores, ghist, top_idx);
    mlp_kernel<<<NQ / QT, 512, 0, stream>>>(f0, f1, f2, scores, top_idx, level_emb,
                                            w1, b1, w2, b2, gate_w, gate_b, G);
    out_kernel<<<dim3(256, NB), 256, 0, stream>>>((const f32x4*)f0, (const f32x4*)f1,
                                                  (const f32x4*)f2, G, rs, (f32x4*)d_out);
}